// Round 19
// baseline (271.990 us; speedup 1.0000x reference)
//
#include <hip/hip_runtime.h>
#include <cstdint>

#define HIDDEN 2048
#define NHEADS 16
#define DH 128
#define BATCH 2
#define SEQ 2048
#define MTOT 4096
#define BH (BATCH * NHEADS)

typedef __attribute__((ext_vector_type(8))) short bf16x8;
typedef __attribute__((ext_vector_type(4))) float f32x4;

// SCALE * log2(e): scores come out of QK^T already in log2 domain
static constexpr float QSCALE = (float)(0.08838834764831845 * 1.4426950408889634);

__device__ __forceinline__ unsigned short f2bf(float f) {
  union { float f; uint32_t u; } v; v.f = f;
  uint32_t r = v.u + 0x7FFFu + ((v.u >> 16) & 1u);
  return (unsigned short)(r >> 16);
}
__device__ __forceinline__ uint32_t cvtpk(float lo, float hi) {
  uint32_t r;
  asm("v_cvt_pk_bf16_f32 %0, %1, %2" : "=v"(r) : "v"(lo), "v"(hi));
  return r;
}
__device__ __forceinline__ f32x4 mfma16(bf16x8 a, bf16x8 b, f32x4 c) {
  return __builtin_amdgcn_mfma_f32_16x16x32_bf16(a, b, c, 0, 0, 0);
}

typedef const __attribute__((address_space(1))) unsigned char* gas1_t;
typedef __attribute__((address_space(3))) unsigned char* las3_t;
__device__ __forceinline__ void gll16(const void* g, void* l) {
  __builtin_amdgcn_global_load_lds((gas1_t)g, (las3_t)l, 16, 0, 0);
}

// ---------------------------------------------------------------------------
// Fused cast: X (8.4M) + Wq/Wk/Wv/Wo (4.2M each), fp32 -> bf16, one launch.
// ---------------------------------------------------------------------------
__global__ __launch_bounds__(256) void cast_all(
    const float* __restrict__ X, const float* __restrict__ Wq,
    const float* __restrict__ Wk, const float* __restrict__ Wv,
    const float* __restrict__ Wo, unsigned short* __restrict__ Xb,
    unsigned short* __restrict__ Wqb, unsigned short* __restrict__ Wkb,
    unsigned short* __restrict__ Wvb, unsigned short* __restrict__ Wob) {
  const int n1 = MTOT * HIDDEN;           // 8388608
  const int i = (blockIdx.x * 256 + threadIdx.x) * 4;
  const float* s;
  unsigned short* d;
  int o;
  if (i < n1) {
    s = X; d = Xb; o = i;
  } else {
    const int j = i - n1;
    const int w = j >> 22;                 // n2 = 2^22
    o = j & ((1 << 22) - 1);
    s = (w == 0) ? Wq : (w == 1) ? Wk : (w == 2) ? Wv : Wo;
    d = (w == 0) ? Wqb : (w == 1) ? Wkb : (w == 2) ? Wvb : Wob;
  }
  float4 f = *(const float4*)&s[o];
  ushort4 u;
  u.x = f2bf(f.x); u.y = f2bf(f.y); u.z = f2bf(f.z); u.w = f2bf(f.w);
  *(ushort4*)&d[o] = u;
}

// ---------------------------------------------------------------------------
// FUSED Q/K/V projection: one block computes Q, K, V outputs for the same
// 128x128 (m,n) tile, staging the A-tile ONCE for all three weight matrices.
// BM=128, BN=128, BK=32, 512 thr / 8 waves (2M x 4N); per-wave 64x32 per
// matrix; acc = 3 x [4][2] f32x4 = 96 VGPR (named arrays, static indexing).
// Per wave-tile: 10 ds_read_b128 : 24 MFMA (vs 16:32 in the split kernel)
// -> ~18% lower LDS traffic per FLOP, A-stage amortized 3x.
// LDS: 3-slot ring, slot = A 8KB @0 + Bq 8KB @8192 + Bk @16384 + Bv @24576
// (32KB/slot, 96KB total -> 1 block/CU). Grid (16,32) = 512 blocks = 2.0
// EXACT capacity rounds (no tail). Prefetch t+2, counted vmcnt(4) once per
// tile (outstanding after stage(t+1) issue = 8; oldest 4 = tile t's loads),
// single s_barrier per tile; hazard discipline identical to the r13 qkv.
// Swizzle (r12-verified, 0 conflicts): 64B rows, 4 chunks, chunk' =
// chunk ^ ((row>>1)&3); staging = linear LDS dest + inverse-permuted global
// source (rule #21). XCD: bx&7 pins each n-panel to one XCD's L2.
// Outputs: Q [BH][S][D] (alpha=QSCALE); K blocked [BH][S/32][d/8][s%32][8];
// V blocked [BH][S/8][D][8].
// ---------------------------------------------------------------------------
template <int VM, bool PF>
__device__ __forceinline__ void qkv3_body(
    int t, char* SM, const unsigned short* aS, const unsigned short* bSq,
    const unsigned short* bSk, const unsigned short* bSv, int wv, int wr,
    int wc, int g, int lr, f32x4 (&accQ)[4][2], f32x4 (&accK)[4][2],
    f32x4 (&accV)[4][2]) {
  const char* slot = SM + (t % 3) * 32768;
  char* slot2 = SM + ((t + 2) % 3) * 32768;
  const size_t ko = (size_t)(t + 2) * 32;
  const int coff = (g ^ ((lr >> 1) & 3)) * 16;
  bf16x8 a[4], bq[2], bk[2], bv[2];
#pragma unroll
  for (int mi = 0; mi < 4; ++mi)
    a[mi] = *(const bf16x8*)(slot + (wr * 64 + mi * 16 + lr) * 64 + coff);
#pragma unroll
  for (int ni = 0; ni < 2; ++ni) {
    const int brow = (wc * 32 + ni * 16 + lr) * 64 + coff;
    bq[ni] = *(const bf16x8*)(slot + 8192 + brow);
    bk[ni] = *(const bf16x8*)(slot + 16384 + brow);
    bv[ni] = *(const bf16x8*)(slot + 24576 + brow);
  }
  if (PF) {
    gll16(aS + ko, slot2 + wv * 1024);
    gll16(bSq + ko, slot2 + 8192 + wv * 1024);
    gll16(bSk + ko, slot2 + 16384 + wv * 1024);
    gll16(bSv + ko, slot2 + 24576 + wv * 1024);
  }
  __builtin_amdgcn_s_setprio(1);
#pragma unroll
  for (int mi = 0; mi < 4; ++mi)
#pragma unroll
    for (int ni = 0; ni < 2; ++ni) {
      accQ[mi][ni] = mfma16(a[mi], bq[ni], accQ[mi][ni]);
      accK[mi][ni] = mfma16(a[mi], bk[ni], accK[mi][ni]);
      accV[mi][ni] = mfma16(a[mi], bv[ni], accV[mi][ni]);
    }
  __builtin_amdgcn_s_setprio(0);
  if (VM == 4) asm volatile("s_waitcnt vmcnt(4)" ::: "memory");
  else if (VM == 0) asm volatile("s_waitcnt vmcnt(0)" ::: "memory");
  if (VM >= 0) __builtin_amdgcn_s_barrier();
}

__global__ __launch_bounds__(512) void gemm_qkv_fused(
    const unsigned short* __restrict__ A, const unsigned short* __restrict__ Wq,
    const unsigned short* __restrict__ Wk, const unsigned short* __restrict__ Wv,
    unsigned short* __restrict__ Qb, unsigned short* __restrict__ Kb,
    unsigned short* __restrict__ Vb) {
  __shared__ __align__(16) char SM[98304];  // 3 slots x 32KB
  const int tid = threadIdx.x;
  const int lane = tid & 63, wv = tid >> 6;
  const int wr = wv >> 2, wc = wv & 3;
  const int g = lane >> 4, lr = lane & 15;
  const int m0 = blockIdx.y * 128, n0 = blockIdx.x * 128;

  // staging chunk: c = tid in [0,512); row = c>>2, chunk j = (c&3)^((row>>1)&3)
  const int row0 = tid >> 2, j0 = (tid & 3) ^ ((row0 >> 1) & 3);
  const unsigned short* aS  = A  + (size_t)(m0 + row0) * HIDDEN + j0 * 8;
  const unsigned short* bSq = Wq + (size_t)(n0 + row0) * HIDDEN + j0 * 8;
  const unsigned short* bSk = Wk + (size_t)(n0 + row0) * HIDDEN + j0 * 8;
  const unsigned short* bSv = Wv + (size_t)(n0 + row0) * HIDDEN + j0 * 8;

  f32x4 accQ[4][2], accK[4][2], accV[4][2];
#pragma unroll
  for (int i = 0; i < 4; ++i)
#pragma unroll
    for (int j = 0; j < 2; ++j) {
      accQ[i][j] = (f32x4){0.f, 0.f, 0.f, 0.f};
      accK[i][j] = (f32x4){0.f, 0.f, 0.f, 0.f};
      accV[i][j] = (f32x4){0.f, 0.f, 0.f, 0.f};
    }

  // prologue: stage tiles 0 and 1
#pragma unroll
  for (int tt = 0; tt < 2; ++tt) {
    char* slot = SM + tt * 32768;
    const size_t ko = (size_t)tt * 32;
    gll16(aS + ko, slot + wv * 1024);
    gll16(bSq + ko, slot + 8192 + wv * 1024);
    gll16(bSk + ko, slot + 16384 + wv * 1024);
    gll16(bSv + ko, slot + 24576 + wv * 1024);
  }
  asm volatile("s_waitcnt vmcnt(4)" ::: "memory");
  __builtin_amdgcn_s_barrier();

  for (int t = 0; t < 62; ++t)
    qkv3_body<4, true>(t, SM, aS, bSq, bSk, bSv, wv, wr, wc, g, lr,
                       accQ, accK, accV);
  qkv3_body<0, false>(62, SM, aS, bSq, bSk, bSv, wv, wr, wc, g, lr,
                      accQ, accK, accV);
  qkv3_body<-1, false>(63, SM, aS, bSq, bSk, bSv, wv, wr, wc, g, lr,
                       accQ, accK, accV);

  // epilogue: three outputs
#pragma unroll
  for (int mi = 0; mi < 4; ++mi)
#pragma unroll
    for (int ni = 0; ni < 2; ++ni)
#pragma unroll
      for (int r = 0; r < 4; ++r) {
        const int row = m0 + wr * 64 + mi * 16 + g * 4 + r;
        const int col = n0 + wc * 32 + ni * 16 + lr;
        const int b = row >> 11, s = row & (SEQ - 1);
        const int h = col >> 7, d = col & (DH - 1);
        const size_t base = (size_t)(b * NHEADS + h) * SEQ * DH;
        Qb[base + (size_t)s * DH + d] = f2bf(accQ[mi][ni][r] * QSCALE);
        Kb[base + (size_t)(s >> 5) * 4096 + (d >> 3) * 256 + (s & 31) * 8 + (d & 7)] =
            f2bf(accK[mi][ni][r]);
        Vb[base + (size_t)(s >> 3) * 1024 + d * 8 + (s & 7)] =
            f2bf(accV[mi][ni][r]);
      }
}

// ---------------------------------------------------------------------------
// O-projection (r13-identical): BM=128, BN=256, BK=64, 512 thr / 8 waves,
// 3-slot ring, single barrier per K-tile, vmcnt(6). grid (8, 32) = 1 round.
// ---------------------------------------------------------------------------
template <int VM, bool PF>
__device__ __forceinline__ void pipe_body(
    int kt, char* SM, const unsigned short* aS0, const unsigned short* aS1,
    const unsigned short* bS0, const unsigned short* bS1,
    const unsigned short* bS2, const unsigned short* bS3, int wv, int wr,
    int wc, int g, int lr, f32x4 (&acc)[4][4]) {
  const char* Ac = SM + (kt % 3) * 49152;
  const char* Bc = Ac + 16384;
  char* slot2 = SM + ((kt + 2) % 3) * 49152;
  const size_t ko = (size_t)(kt + 2) * 64;
  const int rx = lr & 7;
  bf16x8 a0[4], b0[4], a1[4], b1[4];
#pragma unroll
  for (int mi = 0; mi < 4; ++mi)
    a0[mi] = *(const bf16x8*)(Ac + (wr * 64 + mi * 16 + lr) * 128 + ((g ^ rx) * 16));
#pragma unroll
  for (int ni = 0; ni < 4; ++ni)
    b0[ni] = *(const bf16x8*)(Bc + (wc * 64 + ni * 16 + lr) * 128 + ((g ^ rx) * 16));
  if (PF) {
    gll16(aS0 + ko, slot2 + wv * 2048);
    gll16(aS1 + ko, slot2 + wv * 2048 + 1024);
    gll16(bS0 + ko, slot2 + 16384 + wv * 4096);
    gll16(bS1 + ko, slot2 + 16384 + wv * 4096 + 1024);
    gll16(bS2 + ko, slot2 + 16384 + wv * 4096 + 2048);
    gll16(bS3 + ko, slot2 + 16384 + wv * 4096 + 3072);
  }
#pragma unroll
  for (int mi = 0; mi < 4; ++mi)
    a1[mi] = *(const bf16x8*)(Ac + (wr * 64 + mi * 16 + lr) * 128 + (((4 + g) ^ rx) * 16));
#pragma unroll
  for (int ni = 0; ni < 4; ++ni)
    b1[ni] = *(const bf16x8*)(Bc + (wc * 64 + ni * 16 + lr) * 128 + (((4 + g) ^ rx) * 16));
  __builtin_amdgcn_s_setprio(1);
#pragma unroll
  for (int mi = 0; mi < 4; ++mi)
#pragma unroll
    for (int ni = 0; ni < 4; ++ni)
      acc[mi][ni] = mfma16(a0[mi], b0[ni], acc[mi][ni]);
#pragma unroll
  for (int mi = 0; mi < 4; ++mi)
#pragma unroll
    for (int ni = 0; ni < 4; ++ni)
      acc[mi][ni] = mfma16(a1[mi], b1[ni], acc[mi][ni]);
  __builtin_amdgcn_s_setprio(0);
  if (VM == 6) asm volatile("s_waitcnt vmcnt(6)" ::: "memory");
  else if (VM == 0) asm volatile("s_waitcnt vmcnt(0)" ::: "memory");
  if (VM >= 0) __builtin_amdgcn_s_barrier();
}

__global__ __launch_bounds__(512) void gemm_out_pipe(
    const unsigned short* __restrict__ A, const unsigned short* __restrict__ W,
    float* __restrict__ C) {
  __shared__ __align__(16) char SM[147456];
  const int tid = threadIdx.x;
  const int lane = tid & 63, wv = tid >> 6;
  const int wr = wv >> 2, wc = wv & 3;
  const int g = lane >> 4, lr = lane & 15;
  const int m0 = blockIdx.y * 128, n0 = blockIdx.x * 256;

  const int idxA0 = wv * 128 + lane, idxA1 = idxA0 + 64;
  const int rA0 = idxA0 >> 3, cA0 = (idxA0 & 7) ^ (rA0 & 7);
  const int rA1 = idxA1 >> 3, cA1 = (idxA1 & 7) ^ (rA1 & 7);
  const unsigned short* aS0 = A + (size_t)(m0 + rA0) * HIDDEN + cA0 * 8;
  const unsigned short* aS1 = A + (size_t)(m0 + rA1) * HIDDEN + cA1 * 8;
  const int idxB0 = wv * 256 + lane, idxB1 = idxB0 + 64,
            idxB2 = idxB0 + 128, idxB3 = idxB0 + 192;
  const int rB0 = idxB0 >> 3, cB0 = (idxB0 & 7) ^ (rB0 & 7);
  const int rB1 = idxB1 >> 3, cB1 = (idxB1 & 7) ^ (rB1 & 7);
  const int rB2 = idxB2 >> 3, cB2 = (idxB2 & 7) ^ (rB2 & 7);
  const int rB3 = idxB3 >> 3, cB3 = (idxB3 & 7) ^ (rB3 & 7);
  const unsigned short* bS0 = W + (size_t)(n0 + rB0) * HIDDEN + cB0 * 8;
  const unsigned short* bS1 = W + (size_t)(n0 + rB1) * HIDDEN + cB1 * 8;
  const unsigned short* bS2 = W + (size_t)(n0 + rB2) * HIDDEN + cB2 * 8;
  const unsigned short* bS3 = W + (size_t)(n0 + rB3) * HIDDEN + cB3 * 8;

  f32x4 acc[4][4];
#pragma unroll
  for (int i = 0; i < 4; ++i)
#pragma unroll
    for (int j = 0; j < 4; ++j) acc[i][j] = (f32x4){0.f, 0.f, 0.f, 0.f};

#pragma unroll
  for (int tt = 0; tt < 2; ++tt) {
    char* slot = SM + tt * 49152;
    const size_t ko = (size_t)tt * 64;
    gll16(aS0 + ko, slot + wv * 2048);
    gll16(aS1 + ko, slot + wv * 2048 + 1024);
    gll16(bS0 + ko, slot + 16384 + wv * 4096);
    gll16(bS1 + ko, slot + 16384 + wv * 4096 + 1024);
    gll16(bS2 + ko, slot + 16384 + wv * 4096 + 2048);
    gll16(bS3 + ko, slot + 16384 + wv * 4096 + 3072);
  }
  asm volatile("s_waitcnt vmcnt(6)" ::: "memory");
  __builtin_amdgcn_s_barrier();

  for (int kt = 0; kt < 30; ++kt)
    pipe_body<6, true>(kt, SM, aS0, aS1, bS0, bS1, bS2, bS3, wv, wr, wc, g,
                       lr, acc);
  pipe_body<0, false>(30, SM, aS0, aS1, bS0, bS1, bS2, bS3, wv, wr, wc, g,
                      lr, acc);
  pipe_body<-1, false>(31, SM, aS0, aS1, bS0, bS1, bS2, bS3, wv, wr, wc, g,
                       lr, acc);

#pragma unroll
  for (int mi = 0; mi < 4; ++mi)
#pragma unroll
    for (int ni = 0; ni < 4; ++ni)
#pragma unroll
      for (int r = 0; r < 4; ++r) {
        const int row = m0 + wr * 64 + mi * 16 + g * 4 + r;
        const int col = n0 + wc * 64 + ni * 16 + lr;
        C[(size_t)row * HIDDEN + col] = acc[mi][ni][r];
      }
}

// ---------------------------------------------------------------------------
// MFMA flash attention (champion r13 variant): QBLK=64 -> 1024 blocks, 256
// thr / 4 waves, each wave one 16-row m-block. 2-slot K/V ring (LDS 37.9KB
// -> 4 blocks/CU; vmcnt(0)+raw-barrier drain hidden by sibling blocks).
// K blocked [S/32][d/8][s%32][8], V blocked [S/8][D][8]. Log2-domain
// softmax, defer-max THR=8, per-lane deferred l-sum, setprio, head-aligned
// XCD grid (bid&31 = bh).
// ---------------------------------------------------------------------------
__global__ __launch_bounds__(256, 4) void attn_mfma(const unsigned short* __restrict__ Q,
                                                    const unsigned short* __restrict__ K,
                                                    const unsigned short* __restrict__ V,
                                                    unsigned short* __restrict__ Ab) {
  const int bid = blockIdx.x;
  const int bh = bid & 31;            // bid%8 == bh%8 -> head-aligned XCD
  const int q0 = (bid >> 5) * 64;
  const int tid = threadIdx.x;
  const int wv = tid >> 6, lane = tid & 63;
  const int g = lane >> 4, lr = lane & 15;
  const unsigned short* Qh = Q + (size_t)bh * SEQ * DH;
  const unsigned short* Kh = K + (size_t)bh * SEQ * DH;
  const unsigned short* Vh = V + (size_t)bh * SEQ * DH;

  __shared__ __align__(16) unsigned short Kls[2][4096];
  __shared__ __align__(16) unsigned short Vls[2][4096];
  __shared__ __align__(16) unsigned short Pw[4][16][40];

  bf16x8 qf[4];
#pragma unroll
  for (int kb = 0; kb < 4; ++kb)
    qf[kb] = *(const bf16x8*)&Qh[(size_t)(q0 + wv * 16 + lr) * DH + kb * 32 + g * 8];

  f32x4 acc[8];
#pragma unroll
  for (int dn = 0; dn < 8; ++dn) acc[dn] = (f32x4){0.f, 0.f, 0.f, 0.f};
  float mrun = -1e30f;
  float lrun = 0.f;

  // prologue: stage tile 0 into slot 0
#pragma unroll
  for (int j = 0; j < 2; ++j) {
    const int c = j * 256 + tid;
    gll16(Kh + (size_t)c * 8, (char*)&Kls[0][0] + j * 4096 + wv * 1024);
    gll16(Vh + (size_t)c * 8, (char*)&Vls[0][0] + j * 4096 + wv * 1024);
  }

  for (int t = 0; t < 64; ++t) {
    const int cur = t & 1;
    asm volatile("s_waitcnt vmcnt(0)" ::: "memory");
    __builtin_amdgcn_s_barrier();   // separates slot reads (t-1) from writes (t+1)
    if (t + 1 < 64) {
      const unsigned short* Kn = Kh + (size_t)(t + 1) * 4096;
      const unsigned short* Vn = Vh + (size_t)(t + 1) * 4096;
      char* kd = (char*)&Kls[cur ^ 1][0];
      char* vd = (char*)&Vls[cur ^ 1][0];
#pragma unroll
      for (int j = 0; j < 2; ++j) {
        const int c = j * 256 + tid;
        gll16(Kn + (size_t)c * 8, kd + j * 4096 + wv * 1024);
        gll16(Vn + (size_t)c * 8, vd + j * 4096 + wv * 1024);
      }
    }

    const char* Kc = (const char*)&Kls[cur][0];
    const char* Vc = (const char*)&Vls[cur][0];

    f32x4 st0 = (f32x4){0.f, 0.f, 0.f, 0.f};
    f32x4 st1 = (f32x4){0.f, 0.f, 0.f, 0.f};
    __builtin_amdgcn_s_setprio(1);
#pragma unroll
    for (int kb = 0; kb < 4; ++kb) {
      const int cb = (kb * 4 + g) * 32;
      bf16x8 kf0 = *(const bf16x8*)(Kc + (cb + lr) * 16);
      bf16x8 kf1 = *(const bf16x8*)(Kc + (cb + 16 + lr) * 16);
      st0 = mfma16(kf0, qf[kb], st0);
      st1 = mfma16(kf1, qf[kb], st1);
    }
    __builtin_amdgcn_s_setprio(0);
    float mt = fmaxf(fmaxf(fmaxf(st0[0], st0[1]), fmaxf(st0[2], st0[3])),
                     fmaxf(fmaxf(st1[0], st1[1]), fmaxf(st1[2], st1[3])));
    mt = fmaxf(mt, __shfl_xor(mt, 16));
    mt = fmaxf(mt, __shfl_xor(mt, 32));
    if (!__all(mt <= mrun + 8.0f)) {  // rare rescale (defer-max)
      const float mnew = fmaxf(mrun, mt);
      const float corr = __builtin_amdgcn_exp2f(mrun - mnew);
      lrun *= corr;
      mrun = mnew;
      const f32x4 cv = (f32x4){__shfl(corr, g * 4 + 0), __shfl(corr, g * 4 + 1),
                               __shfl(corr, g * 4 + 2), __shfl(corr, g * 4 + 3)};
#pragma unroll
      for (int dn = 0; dn < 8; ++dn) acc[dn] *= cv;
    }
    float p[8], ls = 0.f;
#pragma unroll
    for (int r = 0; r < 4; ++r) {
      p[r] = __builtin_amdgcn_exp2f(st0[r] - mrun);
      p[4 + r] = __builtin_amdgcn_exp2f(st1[r] - mrun);
      ls += p[r] + p[4 + r];
    }
    lrun += ls;  // per-lane partial; cross-lane reduce deferred to end
    uint2 pk0, pk1;
    pk0.x = cvtpk(p[0], p[1]); pk0.y = cvtpk(p[2], p[3]);
    pk1.x = cvtpk(p[4], p[5]); pk1.y = cvtpk(p[6], p[7]);
    *(uint2*)&Pw[wv][lr][4 * g] = pk0;
    *(uint2*)&Pw[wv][lr][16 + 4 * g] = pk1;
    bf16x8 ap = *(const bf16x8*)&Pw[wv][lr][8 * g];
    // PV
    __builtin_amdgcn_s_setprio(1);
#pragma unroll
    for (int dn = 0; dn < 8; ++dn) {
      bf16x8 vf = *(const bf16x8*)(Vc + (g * 128 + dn * 16 + lr) * 16);
      acc[dn] = mfma16(ap, vf, acc[dn]);
    }
    __builtin_amdgcn_s_setprio(0);
  }

  const int b = bh >> 4, h = bh & 15;
  lrun += __shfl_xor(lrun, 16);
  lrun += __shfl_xor(lrun, 32);
  const float inv = 1.f / lrun;
  float ir[4];
#pragma unroll
  for (int r = 0; r < 4; ++r) ir[r] = __shfl(inv, g * 4 + r);
#pragma unroll
  for (int dn = 0; dn < 8; ++dn)
#pragma unroll
    for (int r = 0; r < 4; ++r) {
      const int srow = q0 + wv * 16 + g * 4 + r;
      Ab[((size_t)(b * SEQ + srow) * NHEADS + h) * DH + dn * 16 + lr] =
          f2bf(acc[dn][r] * ir[r]);
    }
}

// ---------------------------------------------------------------------------
extern "C" void kernel_launch(void* const* d_in, const int* in_sizes, int n_in,
                              void* d_out, int out_size, void* d_ws,
                              size_t ws_size, hipStream_t stream) {
  const float* X  = (const float*)d_in[0];
  const float* Wq = (const float*)d_in[1];
  const float* Wk = (const float*)d_in[2];
  const float* Wv = (const float*)d_in[3];
  const float* Wo = (const float*)d_in[4];
  float* out = (float*)d_out;

  const int n1 = MTOT * HIDDEN;    // 8388608
  const int n2 = HIDDEN * HIDDEN;  // 4194304

  char* p = (char*)d_ws;
  unsigned short* Xb  = (unsigned short*)(p + 0);          // 16 MB
  unsigned short* Qb  = (unsigned short*)(p + 16777216);   // 16 MB
  unsigned short* Kb  = (unsigned short*)(p + 33554432);   // 16 MB
  unsigned short* Vb  = (unsigned short*)(p + 50331648);   // 16 MB
  unsigned short* Wqb = (unsigned short*)(p + 67108864);   // 8 MB
  unsigned short* Wkb = (unsigned short*)(p + 75497472);   // 8 MB
  unsigned short* Wvb = (unsigned short*)(p + 83886080);   // 8 MB
  unsigned short* Wob = (unsigned short*)(p + 92274688);   // 8 MB
  unsigned short* Ab  = (unsigned short*)(p + 100663296);  // 16 MB (ends 117440512)

  cast_all<<<(n1 + 4 * n2) / 1024, 256, 0, stream>>>(X, Wq, Wk, Wv, Wo, Xb, Wqb,
                                                     Wkb, Wvb, Wob);

  gemm_qkv_fused<<<dim3(HIDDEN / 128, MTOT / 128), 512, 0, stream>>>(
      Xb, Wqb, Wkb, Wvb, Qb, Kb, Vb);

  attn_mfma<<<dim3(1024), 256, 0, stream>>>(Qb, Kb, Vb, Ab);

  gemm_out_pipe<<<dim3(HIDDEN / 256, MTOT / 128), 512, 0, stream>>>(Ab, Wob, out);
}

// Round 20
// 268.200 us; speedup vs baseline: 1.0141x; 1.0141x over previous
//
#include <hip/hip_runtime.h>
#include <cstdint>

#define HIDDEN 2048
#define NHEADS 16
#define DH 128
#define BATCH 2
#define SEQ 2048
#define MTOT 4096
#define BH (BATCH * NHEADS)

typedef __attribute__((ext_vector_type(8))) short bf16x8;
typedef __attribute__((ext_vector_type(4))) float f32x4;

// SCALE * log2(e): scores come out of QK^T already in log2 domain
static constexpr float QSCALE = (float)(0.08838834764831845 * 1.4426950408889634);

__device__ __forceinline__ unsigned short f2bf(float f) {
  union { float f; uint32_t u; } v; v.f = f;
  uint32_t r = v.u + 0x7FFFu + ((v.u >> 16) & 1u);
  return (unsigned short)(r >> 16);
}
__device__ __forceinline__ uint32_t cvtpk(float lo, float hi) {
  uint32_t r;
  asm("v_cvt_pk_bf16_f32 %0, %1, %2" : "=v"(r) : "v"(lo), "v"(hi));
  return r;
}
__device__ __forceinline__ f32x4 mfma16(bf16x8 a, bf16x8 b, f32x4 c) {
  return __builtin_amdgcn_mfma_f32_16x16x32_bf16(a, b, c, 0, 0, 0);
}

typedef const __attribute__((address_space(1))) unsigned char* gas1_t;
typedef __attribute__((address_space(3))) unsigned char* las3_t;
__device__ __forceinline__ void gll16(const void* g, void* l) {
  __builtin_amdgcn_global_load_lds((gas1_t)g, (las3_t)l, 16, 0, 0);
}

// ---------------------------------------------------------------------------
// Fused cast: X (8.4M) + Wq/Wk/Wv/Wo (4.2M each), fp32 -> bf16, one launch.
// ---------------------------------------------------------------------------
__global__ __launch_bounds__(256) void cast_all(
    const float* __restrict__ X, const float* __restrict__ Wq,
    const float* __restrict__ Wk, const float* __restrict__ Wv,
    const float* __restrict__ Wo, unsigned short* __restrict__ Xb,
    unsigned short* __restrict__ Wqb, unsigned short* __restrict__ Wkb,
    unsigned short* __restrict__ Wvb, unsigned short* __restrict__ Wob) {
  const int n1 = MTOT * HIDDEN;           // 8388608
  const int i = (blockIdx.x * 256 + threadIdx.x) * 4;
  const float* s;
  unsigned short* d;
  int o;
  if (i < n1) {
    s = X; d = Xb; o = i;
  } else {
    const int j = i - n1;
    const int w = j >> 22;                 // n2 = 2^22
    o = j & ((1 << 22) - 1);
    s = (w == 0) ? Wq : (w == 1) ? Wk : (w == 2) ? Wv : Wo;
    d = (w == 0) ? Wqb : (w == 1) ? Wkb : (w == 2) ? Wvb : Wob;
  }
  float4 f = *(const float4*)&s[o];
  ushort4 u;
  u.x = f2bf(f.x); u.y = f2bf(f.y); u.z = f2bf(f.z); u.w = f2bf(f.w);
  *(ushort4*)&d[o] = u;
}

// ---------------------------------------------------------------------------
// Single-barrier deep-pipelined GEMM body (best measured: r9/r13). BM=128,
// BN=256, BK=64, 512 thr / 8 waves (2M x 4N), per-wave 64x64. 3-slot LDS
// ring (49152 B/slot), prefetch kt+2, one barrier per K-tile, vmcnt(6).
// ---------------------------------------------------------------------------
template <int VM, bool PF>
__device__ __forceinline__ void pipe_body(
    int kt, char* SM, const unsigned short* aS0, const unsigned short* aS1,
    const unsigned short* bS0, const unsigned short* bS1,
    const unsigned short* bS2, const unsigned short* bS3, int wv, int wr,
    int wc, int g, int lr, f32x4 (&acc)[4][4]) {
  const char* Ac = SM + (kt % 3) * 49152;
  const char* Bc = Ac + 16384;
  char* slot2 = SM + ((kt + 2) % 3) * 49152;
  const size_t ko = (size_t)(kt + 2) * 64;
  const int rx = lr & 7;
  bf16x8 a0[4], b0[4], a1[4], b1[4];
#pragma unroll
  for (int mi = 0; mi < 4; ++mi)
    a0[mi] = *(const bf16x8*)(Ac + (wr * 64 + mi * 16 + lr) * 128 + ((g ^ rx) * 16));
#pragma unroll
  for (int ni = 0; ni < 4; ++ni)
    b0[ni] = *(const bf16x8*)(Bc + (wc * 64 + ni * 16 + lr) * 128 + ((g ^ rx) * 16));
  if (PF) {
    gll16(aS0 + ko, slot2 + wv * 2048);
    gll16(aS1 + ko, slot2 + wv * 2048 + 1024);
    gll16(bS0 + ko, slot2 + 16384 + wv * 4096);
    gll16(bS1 + ko, slot2 + 16384 + wv * 4096 + 1024);
    gll16(bS2 + ko, slot2 + 16384 + wv * 4096 + 2048);
    gll16(bS3 + ko, slot2 + 16384 + wv * 4096 + 3072);
  }
#pragma unroll
  for (int mi = 0; mi < 4; ++mi)
    a1[mi] = *(const bf16x8*)(Ac + (wr * 64 + mi * 16 + lr) * 128 + (((4 + g) ^ rx) * 16));
#pragma unroll
  for (int ni = 0; ni < 4; ++ni)
    b1[ni] = *(const bf16x8*)(Bc + (wc * 64 + ni * 16 + lr) * 128 + (((4 + g) ^ rx) * 16));
  __builtin_amdgcn_s_setprio(1);
#pragma unroll
  for (int mi = 0; mi < 4; ++mi)
#pragma unroll
    for (int ni = 0; ni < 4; ++ni)
      acc[mi][ni] = mfma16(a0[mi], b0[ni], acc[mi][ni]);
#pragma unroll
  for (int mi = 0; mi < 4; ++mi)
#pragma unroll
    for (int ni = 0; ni < 4; ++ni)
      acc[mi][ni] = mfma16(a1[mi], b1[ni], acc[mi][ni]);
  __builtin_amdgcn_s_setprio(0);
  if (VM == 6) asm volatile("s_waitcnt vmcnt(6)" ::: "memory");
  else if (VM == 0) asm volatile("s_waitcnt vmcnt(0)" ::: "memory");
  if (VM >= 0) __builtin_amdgcn_s_barrier();
}

// Per-thread staging source pointers (inverse of the LDS chunk permutation).
#define PIPE_SETUP(Abase, Bbase)                                              \
  const int idxA0 = wv * 128 + lane, idxA1 = idxA0 + 64;                      \
  const int rA0 = idxA0 >> 3, cA0 = (idxA0 & 7) ^ (rA0 & 7);                  \
  const int rA1 = idxA1 >> 3, cA1 = (idxA1 & 7) ^ (rA1 & 7);                  \
  const unsigned short* aS0 = (Abase) + (size_t)(m0 + rA0) * HIDDEN + cA0 * 8;\
  const unsigned short* aS1 = (Abase) + (size_t)(m0 + rA1) * HIDDEN + cA1 * 8;\
  const int idxB0 = wv * 256 + lane, idxB1 = idxB0 + 64,                      \
            idxB2 = idxB0 + 128, idxB3 = idxB0 + 192;                         \
  const int rB0 = idxB0 >> 3, cB0 = (idxB0 & 7) ^ (rB0 & 7);                  \
  const int rB1 = idxB1 >> 3, cB1 = (idxB1 & 7) ^ (rB1 & 7);                  \
  const int rB2 = idxB2 >> 3, cB2 = (idxB2 & 7) ^ (rB2 & 7);                  \
  const int rB3 = idxB3 >> 3, cB3 = (idxB3 & 7) ^ (rB3 & 7);                  \
  const unsigned short* bS0 = (Bbase) + (size_t)(n0 + rB0) * HIDDEN + cB0 * 8;\
  const unsigned short* bS1 = (Bbase) + (size_t)(n0 + rB1) * HIDDEN + cB1 * 8;\
  const unsigned short* bS2 = (Bbase) + (size_t)(n0 + rB2) * HIDDEN + cB2 * 8;\
  const unsigned short* bS3 = (Bbase) + (size_t)(n0 + rB3) * HIDDEN + cB3 * 8;

#define PIPE_PROLOGUE()                                                       \
  _Pragma("unroll") for (int tt = 0; tt < 2; ++tt) {                          \
    char* slot = SM + tt * 49152;                                             \
    const size_t ko = (size_t)tt * 64;                                        \
    gll16(aS0 + ko, slot + wv * 2048);                                        \
    gll16(aS1 + ko, slot + wv * 2048 + 1024);                                 \
    gll16(bS0 + ko, slot + 16384 + wv * 4096);                                \
    gll16(bS1 + ko, slot + 16384 + wv * 4096 + 1024);                         \
    gll16(bS2 + ko, slot + 16384 + wv * 4096 + 2048);                         \
    gll16(bS3 + ko, slot + 16384 + wv * 4096 + 3072);                         \
  }                                                                           \
  asm volatile("s_waitcnt vmcnt(6)" ::: "memory");                            \
  __builtin_amdgcn_s_barrier();

#define PIPE_LOOP()                                                           \
  for (int kt = 0; kt < 30; ++kt)                                             \
    pipe_body<6, true>(kt, SM, aS0, aS1, bS0, bS1, bS2, bS3, wv, wr, wc, g,   \
                       lr, acc);                                              \
  pipe_body<0, false>(30, SM, aS0, aS1, bS0, bS1, bS2, bS3, wv, wr, wc, g,    \
                      lr, acc);                                               \
  pipe_body<-1, false>(31, SM, aS0, aS1, bS0, bS1, bS2, bS3, wv, wr, wc, g,   \
                       lr, acc);

// ---------------------------------------------------------------------------
// Fused Q/K/V projection. grid (24, 32): which = x>>3, n0 = (x&7)*256.
// which 0: Q [BH][S][D] (alpha=QSCALE); 1: K blocked [BH][S/32][d/8][s%32][8];
// 2: V blocked [BH][S/8][D][8].
// ---------------------------------------------------------------------------
__global__ __launch_bounds__(512) void gemm_qkv_pipe(
    const unsigned short* __restrict__ A, const unsigned short* __restrict__ Wq,
    const unsigned short* __restrict__ Wk, const unsigned short* __restrict__ Wv,
    unsigned short* __restrict__ Qb, unsigned short* __restrict__ Kb,
    unsigned short* __restrict__ Vb) {
  __shared__ __align__(16) char SM[147456];
  const int tid = threadIdx.x;
  const int lane = tid & 63, wv = tid >> 6;
  const int wr = wv >> 2, wc = wv & 3;
  const int g = lane >> 4, lr = lane & 15;
  const int which = blockIdx.x >> 3;
  const int m0 = blockIdx.y * 128, n0 = (blockIdx.x & 7) * 256;
  const unsigned short* W = (which == 0) ? Wq : (which == 1) ? Wk : Wv;

  PIPE_SETUP(A, W)

  f32x4 acc[4][4];
#pragma unroll
  for (int i = 0; i < 4; ++i)
#pragma unroll
    for (int j = 0; j < 4; ++j) acc[i][j] = (f32x4){0.f, 0.f, 0.f, 0.f};

  PIPE_PROLOGUE()
  PIPE_LOOP()

  const float alpha = (which == 0) ? QSCALE : 1.0f;
  unsigned short* C = (which == 0) ? Qb : (which == 1) ? Kb : Vb;
#pragma unroll
  for (int mi = 0; mi < 4; ++mi)
#pragma unroll
    for (int ni = 0; ni < 4; ++ni)
#pragma unroll
      for (int r = 0; r < 4; ++r) {
        const int row = m0 + wr * 64 + mi * 16 + g * 4 + r;
        const int col = n0 + wc * 64 + ni * 16 + lr;
        const unsigned short v = f2bf(acc[mi][ni][r] * alpha);
        const int b = row >> 11, s = row & (SEQ - 1);
        const int h = col >> 7, d = col & (DH - 1);
        const size_t base = (size_t)(b * NHEADS + h) * SEQ * DH;
        if (which == 0)
          C[base + (size_t)s * DH + d] = v;
        else if (which == 1)
          C[base + (size_t)(s >> 5) * 4096 + (d >> 3) * 256 + (s & 31) * 8 + (d & 7)] = v;
        else
          C[base + (size_t)(s >> 3) * 1024 + d * 8 + (s & 7)] = v;
      }
}

// ---------------------------------------------------------------------------
// O-projection: C(f32)[4096][2048] = A_bf16 @ Wo_bf16^T. grid (8, 32).
// ---------------------------------------------------------------------------
__global__ __launch_bounds__(512) void gemm_out_pipe(
    const unsigned short* __restrict__ A, const unsigned short* __restrict__ W,
    float* __restrict__ C) {
  __shared__ __align__(16) char SM[147456];
  const int tid = threadIdx.x;
  const int lane = tid & 63, wv = tid >> 6;
  const int wr = wv >> 2, wc = wv & 3;
  const int g = lane >> 4, lr = lane & 15;
  const int m0 = blockIdx.y * 128, n0 = blockIdx.x * 256;

  PIPE_SETUP(A, W)

  f32x4 acc[4][4];
#pragma unroll
  for (int i = 0; i < 4; ++i)
#pragma unroll
    for (int j = 0; j < 4; ++j) acc[i][j] = (f32x4){0.f, 0.f, 0.f, 0.f};

  PIPE_PROLOGUE()
  PIPE_LOOP()

#pragma unroll
  for (int mi = 0; mi < 4; ++mi)
#pragma unroll
    for (int ni = 0; ni < 4; ++ni)
#pragma unroll
      for (int r = 0; r < 4; ++r) {
        const int row = m0 + wr * 64 + mi * 16 + g * 4 + r;
        const int col = n0 + wc * 64 + ni * 16 + lr;
        C[(size_t)row * HIDDEN + col] = acc[mi][ni][r];
      }
}

// ---------------------------------------------------------------------------
// MFMA flash attention (champion r13 variant): QBLK=64 -> 1024 blocks, 256
// thr / 4 waves, each wave one 16-row m-block. 2-slot K/V ring (LDS 37.9KB
// -> 4 blocks/CU = 16 waves/CU; the per-tile vmcnt(0)+raw-barrier drain is
// hidden by sibling blocks, m114). K blocked [S/32][d/8][s%32][8], V blocked
// [S/8][D][8] -> tile staging = 2 contiguous 8KB gll16 groups. Log2-domain
// softmax, defer-max THR=8, per-lane deferred l-sum, setprio, head-aligned
// XCD grid (bid&31 = bh).
// ---------------------------------------------------------------------------
__global__ __launch_bounds__(256, 4) void attn_mfma(const unsigned short* __restrict__ Q,
                                                    const unsigned short* __restrict__ K,
                                                    const unsigned short* __restrict__ V,
                                                    unsigned short* __restrict__ Ab) {
  const int bid = blockIdx.x;
  const int bh = bid & 31;            // bid%8 == bh%8 -> head-aligned XCD
  const int q0 = (bid >> 5) * 64;
  const int tid = threadIdx.x;
  const int wv = tid >> 6, lane = tid & 63;
  const int g = lane >> 4, lr = lane & 15;
  const unsigned short* Qh = Q + (size_t)bh * SEQ * DH;
  const unsigned short* Kh = K + (size_t)bh * SEQ * DH;
  const unsigned short* Vh = V + (size_t)bh * SEQ * DH;

  __shared__ __align__(16) unsigned short Kls[2][4096];
  __shared__ __align__(16) unsigned short Vls[2][4096];
  __shared__ __align__(16) unsigned short Pw[4][16][40];

  bf16x8 qf[4];
#pragma unroll
  for (int kb = 0; kb < 4; ++kb)
    qf[kb] = *(const bf16x8*)&Qh[(size_t)(q0 + wv * 16 + lr) * DH + kb * 32 + g * 8];

  f32x4 acc[8];
#pragma unroll
  for (int dn = 0; dn < 8; ++dn) acc[dn] = (f32x4){0.f, 0.f, 0.f, 0.f};
  float mrun = -1e30f;
  float lrun = 0.f;

  // prologue: stage tile 0 into slot 0
#pragma unroll
  for (int j = 0; j < 2; ++j) {
    const int c = j * 256 + tid;
    gll16(Kh + (size_t)c * 8, (char*)&Kls[0][0] + j * 4096 + wv * 1024);
    gll16(Vh + (size_t)c * 8, (char*)&Vls[0][0] + j * 4096 + wv * 1024);
  }

  for (int t = 0; t < 64; ++t) {
    const int cur = t & 1;
    asm volatile("s_waitcnt vmcnt(0)" ::: "memory");
    __builtin_amdgcn_s_barrier();   // separates slot reads (t-1) from writes (t+1)
    if (t + 1 < 64) {
      const unsigned short* Kn = Kh + (size_t)(t + 1) * 4096;
      const unsigned short* Vn = Vh + (size_t)(t + 1) * 4096;
      char* kd = (char*)&Kls[cur ^ 1][0];
      char* vd = (char*)&Vls[cur ^ 1][0];
#pragma unroll
      for (int j = 0; j < 2; ++j) {
        const int c = j * 256 + tid;
        gll16(Kn + (size_t)c * 8, kd + j * 4096 + wv * 1024);
        gll16(Vn + (size_t)c * 8, vd + j * 4096 + wv * 1024);
      }
    }

    const char* Kc = (const char*)&Kls[cur][0];
    const char* Vc = (const char*)&Vls[cur][0];

    f32x4 st0 = (f32x4){0.f, 0.f, 0.f, 0.f};
    f32x4 st1 = (f32x4){0.f, 0.f, 0.f, 0.f};
    __builtin_amdgcn_s_setprio(1);
#pragma unroll
    for (int kb = 0; kb < 4; ++kb) {
      const int cb = (kb * 4 + g) * 32;
      bf16x8 kf0 = *(const bf16x8*)(Kc + (cb + lr) * 16);
      bf16x8 kf1 = *(const bf16x8*)(Kc + (cb + 16 + lr) * 16);
      st0 = mfma16(kf0, qf[kb], st0);
      st1 = mfma16(kf1, qf[kb], st1);
    }
    __builtin_amdgcn_s_setprio(0);
    float mt = fmaxf(fmaxf(fmaxf(st0[0], st0[1]), fmaxf(st0[2], st0[3])),
                     fmaxf(fmaxf(st1[0], st1[1]), fmaxf(st1[2], st1[3])));
    mt = fmaxf(mt, __shfl_xor(mt, 16));
    mt = fmaxf(mt, __shfl_xor(mt, 32));
    if (!__all(mt <= mrun + 8.0f)) {  // rare rescale (defer-max)
      const float mnew = fmaxf(mrun, mt);
      const float corr = __builtin_amdgcn_exp2f(mrun - mnew);
      lrun *= corr;
      mrun = mnew;
      const f32x4 cv = (f32x4){__shfl(corr, g * 4 + 0), __shfl(corr, g * 4 + 1),
                               __shfl(corr, g * 4 + 2), __shfl(corr, g * 4 + 3)};
#pragma unroll
      for (int dn = 0; dn < 8; ++dn) acc[dn] *= cv;
    }
    float p[8], ls = 0.f;
#pragma unroll
    for (int r = 0; r < 4; ++r) {
      p[r] = __builtin_amdgcn_exp2f(st0[r] - mrun);
      p[4 + r] = __builtin_amdgcn_exp2f(st1[r] - mrun);
      ls += p[r] + p[4 + r];
    }
    lrun += ls;  // per-lane partial; cross-lane reduce deferred to end
    uint2 pk0, pk1;
    pk0.x = cvtpk(p[0], p[1]); pk0.y = cvtpk(p[2], p[3]);
    pk1.x = cvtpk(p[4], p[5]); pk1.y = cvtpk(p[6], p[7]);
    *(uint2*)&Pw[wv][lr][4 * g] = pk0;
    *(uint2*)&Pw[wv][lr][16 + 4 * g] = pk1;
    bf16x8 ap = *(const bf16x8*)&Pw[wv][lr][8 * g];
    // PV
    __builtin_amdgcn_s_setprio(1);
#pragma unroll
    for (int dn = 0; dn < 8; ++dn) {
      bf16x8 vf = *(const bf16x8*)(Vc + (g * 128 + dn * 16 + lr) * 16);
      acc[dn] = mfma16(ap, vf, acc[dn]);
    }
    __builtin_amdgcn_s_setprio(0);
  }

  const int b = bh >> 4, h = bh & 15;
  lrun += __shfl_xor(lrun, 16);
  lrun += __shfl_xor(lrun, 32);
  const float inv = 1.f / lrun;
  float ir[4];
#pragma unroll
  for (int r = 0; r < 4; ++r) ir[r] = __shfl(inv, g * 4 + r);
#pragma unroll
  for (int dn = 0; dn < 8; ++dn)
#pragma unroll
    for (int r = 0; r < 4; ++r) {
      const int srow = q0 + wv * 16 + g * 4 + r;
      Ab[((size_t)(b * SEQ + srow) * NHEADS + h) * DH + dn * 16 + lr] =
          f2bf(acc[dn][r] * ir[r]);
    }
}

// ---------------------------------------------------------------------------
extern "C" void kernel_launch(void* const* d_in, const int* in_sizes, int n_in,
                              void* d_out, int out_size, void* d_ws,
                              size_t ws_size, hipStream_t stream) {
  const float* X  = (const float*)d_in[0];
  const float* Wq = (const float*)d_in[1];
  const float* Wk = (const float*)d_in[2];
  const float* Wv = (const float*)d_in[3];
  const float* Wo = (const float*)d_in[4];
  float* out = (float*)d_out;

  const int n1 = MTOT * HIDDEN;    // 8388608
  const int n2 = HIDDEN * HIDDEN;  // 4194304

  char* p = (char*)d_ws;
  unsigned short* Xb  = (unsigned short*)(p + 0);          // 16 MB
  unsigned short* Qb  = (unsigned short*)(p + 16777216);   // 16 MB
  unsigned short* Kb  = (unsigned short*)(p + 33554432);   // 16 MB
  unsigned short* Vb  = (unsigned short*)(p + 50331648);   // 16 MB
  unsigned short* Wqb = (unsigned short*)(p + 67108864);   // 8 MB
  unsigned short* Wkb = (unsigned short*)(p + 75497472);   // 8 MB
  unsigned short* Wvb = (unsigned short*)(p + 83886080);   // 8 MB
  unsigned short* Wob = (unsigned short*)(p + 92274688);   // 8 MB
  unsigned short* Ab  = (unsigned short*)(p + 100663296);  // 16 MB (ends 117440512)

  cast_all<<<(n1 + 4 * n2) / 1024, 256, 0, stream>>>(X, Wq, Wk, Wv, Wo, Xb, Wqb,
                                                     Wkb, Wvb, Wob);

  gemm_qkv_pipe<<<dim3(24, MTOT / 128), 512, 0, stream>>>(Xb, Wqb, Wkb, Wvb,
                                                          Qb, Kb, Vb);

  attn_mfma<<<dim3(1024), 256, 0, stream>>>(Qb, Kb, Vb, Ab);

  gemm_out_pipe<<<dim3(HIDDEN / 256, MTOT / 128), 512, 0, stream>>>(Ab, Wob, out);
}